// Round 4
// baseline (412.856 us; speedup 1.0000x reference)
//
#include <hip/hip_runtime.h>
#include <cstdint>
#include <cstddef>

#define B_   16
#define L_   2048
#define H_   1024
#define S_   32
#define P_   256
#define NASP 8
#define NRAT 5
#define M_   (B_*L_)   /* 32768 */
#define N_   (2*P_)    /* 512  */

typedef unsigned short u16;
typedef __bf16 bf16;
typedef u16  u16x4  __attribute__((ext_vector_type(4)));
typedef u16  u16x8  __attribute__((ext_vector_type(8)));
typedef bf16 bf16x8 __attribute__((ext_vector_type(8)));
typedef float f32x4 __attribute__((ext_vector_type(4)));

// f32 -> bf16 bits (round-to-nearest-even), bf16 bits -> f32.
__device__ __forceinline__ u16 f2b(float f){
  unsigned int u = __float_as_uint(f);
  u += 0x7FFFu + ((u >> 16) & 1u);
  return (u16)(u >> 16);
}
__device__ __forceinline__ float b2f(u16 v){
  return __uint_as_float(((unsigned int)v) << 16);
}

// async global->LDS, 16B per lane; LDS dest is wave-uniform base + lane*16.
__device__ __forceinline__ void gload_lds16(const u16* g, u16* l){
  __builtin_amdgcn_global_load_lds(
      (const __attribute__((address_space(1))) unsigned int*)g,
      (__attribute__((address_space(3))) unsigned int*)l, 16, 0, 0);
}

// ---------------------------------------------------------------- utilities
__device__ __forceinline__ float2 block_reduce2(float a, float b){
  __shared__ float sh[8];
  #pragma unroll
  for (int o = 32; o > 0; o >>= 1){
    a += __shfl_down(a, o, 64);
    b += __shfl_down(b, o, 64);
  }
  int w = threadIdx.x >> 6;
  if ((threadIdx.x & 63) == 0){ sh[w] = a; sh[w + 4] = b; }
  __syncthreads();
  float2 r;
  r.x = sh[0] + sh[1] + sh[2] + sh[3];
  r.y = sh[4] + sh[5] + sh[6] + sh[7];
  __syncthreads();
  return r;
}

// ------------------------------------------------- K0a: fold LN into weights
__global__ void fold_k(const float* __restrict__ Wa, const float* __restrict__ Ws,
                       const float* __restrict__ sa, const float* __restrict__ ba,
                       const float* __restrict__ ss, const float* __restrict__ bs,
                       u16* __restrict__ WcT, float* __restrict__ biasc){
  int n = blockIdx.x;                 // 0..511
  const float* W; const float* sc; const float* bi; int col;
  if (n < P_){ W = Wa; sc = sa; bi = ba; col = n; }
  else       { W = Ws; sc = ss; bi = bs; col = n - P_; }
  float bacc = 0.f;
  #pragma unroll
  for (int i = 0; i < 4; ++i){
    int k = threadIdx.x + i * 256;
    float w = W[(size_t)k * P_ + col];
    WcT[(size_t)n * H_ + k] = f2b(w * sc[k]);
    bacc += w * bi[k];
  }
  float2 r = block_reduce2(bacc, 0.f);
  if (threadIdx.x == 0) biasc[n] = r.x;
}

// --------------------------------------------- K0b: sentence marker indices
__global__ void markers_k(const int* __restrict__ p_index, int* __restrict__ pi){
  int b = blockIdx.x;
  int lane = threadIdx.x;             // 64 threads = 1 wave
  int cnt = 0;
  for (int c = 0; c < L_ / 64; ++c){
    int pos = c * 64 + lane;
    bool f = p_index[(size_t)b * L_ + pos] > 0;
    unsigned long long m = __ballot(f);
    int before = __popcll(m & ((1ull << lane) - 1ull));
    if (f){
      int idx = cnt + before;
      if (idx < S_) pi[b * S_ + idx] = pos;
    }
    cnt += __popcll(m);
  }
}

// -------------------- K1: fused per-row LN stats + normalize -> bf16 xhat
// FUSE_ECHO: also emit the verbatim copy of x into the echo output, saving
// the separate copy_k 134MB re-read (only used when proj/xhat live in ws).
template<bool FUSE_ECHO>
__global__ void stats_xhat_k(const float* __restrict__ x, u16* __restrict__ xhat,
                             float4* __restrict__ echo){
  int row = blockIdx.x;
  int t = threadIdx.x;
  float4 v = ((const float4*)(x + (size_t)row * H_))[t];
  if (FUSE_ECHO) echo[(size_t)row * (H_ / 4) + t] = v;
  float s  = v.x + v.y + v.z + v.w;
  float ss = v.x*v.x + v.y*v.y + v.z*v.z + v.w*v.w;
  float2 r = block_reduce2(s, ss);
  float mean = r.x * (1.f / H_);
  float var  = fmaxf(r.y * (1.f / H_) - mean * mean, 0.f);
  float rstd = rsqrtf(var + 1e-5f);
  u16x4 o;
  o[0] = f2b((v.x - mean) * rstd);
  o[1] = f2b((v.y - mean) * rstd);
  o[2] = f2b((v.z - mean) * rstd);
  o[3] = f2b((v.w - mean) * rstd);
  ((u16x4*)(xhat + (size_t)row * H_))[t] = o;
}

// --------------------------- K2: GEMM (bf16 A from xhat) + bias + GELU
// 128x128 tile, BK=32, 4 waves (2x2), 4x4 16x16x32 MFMA/wave.
// T3 minimal 2-phase pipeline: double-buffered LDS; STAGE(tile t+1) issued
// BEFORE compute(tile t); ONE barrier per K-step (drains vmcnt+lgkm) so the
// next tile's global_load_lds latency hides under ds_read+MFMA of this tile.
// Both-sides k-chunk XOR swizzle (chunk ^= (row>>1)&3): linear LDS dest +
// inverse-swizzled global SOURCE + swizzled ds_read (rule #21).
// XCD swizzle: 4 n-tiles of one m-tile adjacent on one XCD -> A L2-resident.
__global__ __launch_bounds__(256) void gemm_k(const u16* __restrict__ xhat,
                                              const u16* __restrict__ WcT,
                                              const float* __restrict__ biasc,
                                              u16* __restrict__ proj){
  __shared__ __align__(16) u16 As[2 * 128 * 32];   // 2 x 8 KB
  __shared__ __align__(16) u16 Bs[2 * 128 * 32];   // 2 x 8 KB
  int t = threadIdx.x;
  unsigned int l = blockIdx.x;          // 0..1023
  unsigned int xcd  = l & 7;
  unsigned int slot = l >> 3;           // 0..127
  int nbase = (int)(slot & 3) * 128;
  int mbase = (int)(xcd * 32 + (slot >> 2)) * 128;

  int w = t >> 6, lane = t & 63;
  int wr = w >> 1, wc = w & 1;
  int quad = lane >> 4, l15 = lane & 15;

  // Staging: instr j = w*2+i covers rows j*16..j*16+15 (16 rows x 64B = 1KB).
  // lane -> row j*16 + (lane>>2); dest chunk lane&3 (linear); source chunk
  // g = (lane&3) ^ ((lane>>3)&3)  [= (lane&3) ^ ((row>>1)&3)].
  int g = (lane & 3) ^ ((lane >> 3) & 3);
  int r0 = (w * 2 + 0) * 16 + (lane >> 2);
  int r1 = (w * 2 + 1) * 16 + (lane >> 2);
  const u16* gA0 = xhat + (size_t)(mbase + r0) * H_ + g * 8;
  const u16* gA1 = xhat + (size_t)(mbase + r1) * H_ + g * 8;
  const u16* gB0 = WcT  + (size_t)(nbase + r0) * H_ + g * 8;
  const u16* gB1 = WcT  + (size_t)(nbase + r1) * H_ + g * 8;

  f32x4 acc[4][4] = {};

  auto stage = [&](int bb, int kk){
    u16* a = As + bb * 4096 + (w * 2) * 512;
    u16* b = Bs + bb * 4096 + (w * 2) * 512;
    gload_lds16(gA0 + kk, a);
    gload_lds16(gA1 + kk, a + 512);
    gload_lds16(gB0 + kk, b);
    gload_lds16(gB1 + kk, b + 512);
  };
  auto compute = [&](int bb){
    const u16* ab = As + bb * 4096;
    const u16* bb_ = Bs + bb * 4096;
    bf16x8 af[4], bfr[4];
    #pragma unroll
    for (int im = 0; im < 4; ++im){
      int R = wr * 64 + im * 16 + l15;
      int cq = quad ^ ((R >> 1) & 3);
      af[im] = *reinterpret_cast<const bf16x8*>(&ab[R * 32 + cq * 8]);
    }
    #pragma unroll
    for (int in = 0; in < 4; ++in){
      int R = wc * 64 + in * 16 + l15;
      int cq = quad ^ ((R >> 1) & 3);
      bfr[in] = *reinterpret_cast<const bf16x8*>(&bb_[R * 32 + cq * 8]);
    }
    #pragma unroll
    for (int im = 0; im < 4; ++im)
      #pragma unroll
      for (int in = 0; in < 4; ++in)
        acc[im][in] = __builtin_amdgcn_mfma_f32_16x16x32_bf16(af[im], bfr[in], acc[im][in], 0, 0, 0);
  };

  // prologue: tile 0 -> buf 0
  stage(0, 0);
  __syncthreads();                       // vmcnt(0): buf0 ready
  int cur = 0;
  for (int step = 0; step < 31; ++step){
    stage(cur ^ 1, (step + 1) * 32);     // issue NEXT tile's loads first
    compute(cur);                        // ds_read + 16 MFMA hide the latency
    __syncthreads();                     // drains vmcnt+lgkm: next buf ready
    cur ^= 1;
  }
  compute(cur);                          // last tile, no prefetch

  // epilogue: bias + exact gelu + bf16 store
  #pragma unroll
  for (int in = 0; in < 4; ++in){
    int col = nbase + wc * 64 + in * 16 + l15;
    float bv = biasc[col];
    #pragma unroll
    for (int im = 0; im < 4; ++im){
      #pragma unroll
      for (int r = 0; r < 4; ++r){
        int rowg = mbase + wr * 64 + im * 16 + quad * 4 + r;
        float vv = acc[im][in][r] + bv;
        float gl = 0.5f * vv * (1.0f + erff(vv * 0.70710678118654752f));
        proj[(size_t)rowg * N_ + col] = f2b(gl);
      }
    }
  }
}

// ------------------------------------------------- K3: segment (span) means
// 1024 threads = 16 waves per block; each wave reads one FULL 1KB row
// (64 lanes x 16B), 16 rows in flight per iteration. 512 blocks x 1024 thr
// = exactly 2 blocks/CU = 32 waves/CU. Cross-wave reduce through 32KB LDS.
__global__ __launch_bounds__(1024) void segmean_k(const u16* __restrict__ proj,
                                                  const int* __restrict__ pi,
                                                  float* __restrict__ sent){
  int b = blockIdx.x, j = blockIdx.y;
  int t = threadIdx.x;
  int rg   = t >> 6;        // 0..15 (wave id = row group)
  int lane = t & 63;        // lane covers cols [lane*8, lane*8+8)
  int end   = pi[b * S_ + j];
  int start = (j == 0) ? 0 : (pi[b * S_ + j - 1] + 1);
  end   = min(max(end, 0), L_);
  start = min(max(start, 0), end);
  int cnt = max(end - start, 1);
  float inv = 1.0f / (float)cnt;

  float s[8] = {};
  const u16* base = proj + ((size_t)b * L_ + start) * N_ + lane * 8;
  for (int r = rg; r < cnt; r += 16){
    u16x8 v = *reinterpret_cast<const u16x8*>(base + (size_t)r * N_);
    #pragma unroll
    for (int k = 0; k < 8; ++k) s[k] += b2f(v[k]);
  }

  __shared__ float sh[16][N_];           // 32 KB
  #pragma unroll
  for (int k = 0; k < 8; ++k) sh[rg][lane * 8 + k] = s[k];
  __syncthreads();

  if (t < N_){
    float acc = 0.f;
    #pragma unroll
    for (int g = 0; g < 16; ++g) acc += sh[g][t];
    sent[((size_t)b * S_ + j) * N_ + t] = acc * inv;
  }
}

// --------------------- K4: aspect head: LN + (256x9) matmul + softmax
__global__ void aspect_k(const float* __restrict__ sent,
                         const float* __restrict__ lns, const float* __restrict__ lnb,
                         const float* __restrict__ Wasp,
                         float* __restrict__ out_adoc, float* __restrict__ aw){
  int sidx = blockIdx.x;   // 0..511
  int t = threadIdx.x;
  float a = sent[(size_t)sidx * N_ + t];        // a-branch = cols [0,256)
  float2 r = block_reduce2(a, a * a);
  float mean = r.x * (1.f / P_);
  float var  = fmaxf(r.y * (1.f / P_) - mean * mean, 0.f);
  float rstd = rsqrtf(var + 1e-5f);
  __shared__ float shv[P_];
  shv[t] = (a - mean) * rstd * lns[t] + lnb[t];
  __syncthreads();
  __shared__ float lg[NASP + 1];
  if (t < NASP + 1){
    float acc = 0.f;
    for (int p = 0; p < P_; ++p) acc += shv[p] * Wasp[p * (NASP + 1) + t];
    lg[t] = acc;
  }
  __syncthreads();
  __shared__ float pr[NASP + 1];
  if (t == 0){
    float m = lg[0];
    #pragma unroll
    for (int i = 1; i < NASP + 1; ++i) m = fmaxf(m, lg[i]);
    float s = 0.f;
    #pragma unroll
    for (int i = 0; i < NASP + 1; ++i){ float e = expf(lg[i] - m); pr[i] = e; s += e; }
    float is = 1.f / s;
    #pragma unroll
    for (int i = 0; i < NASP + 1; ++i) pr[i] *= is;
  }
  __syncthreads();
  if (t < NASP + 1) out_adoc[(size_t)sidx * (NASP + 1) + t] = pr[t];
  if (t < NASP)     aw[(size_t)sidx * NASP + t] = pr[t];
}

// ---------- K5: doc pooling + LN + (256x5) matmul -> result
__global__ void result_k(const float* __restrict__ sent, const float* __restrict__ aw,
                         const float* __restrict__ lns, const float* __restrict__ lnb,
                         const float* __restrict__ Wse, float* __restrict__ out){
  int ba = blockIdx.x;          // b*8 + aspect
  int b = ba >> 3, a = ba & 7;
  int t = threadIdx.x;
  float acc = 0.f, wsum = 0.f;
  for (int s2 = 0; s2 < S_; ++s2){
    float w = aw[((size_t)(b * S_ + s2)) * NASP + a];
    acc  += w * sent[((size_t)(b * S_ + s2)) * N_ + P_ + t];  // s-branch
    wsum += w;
  }
  float d = acc / fmaxf(wsum, 1e-20f);
  float2 r = block_reduce2(d, d * d);
  float mean = r.x * (1.f / P_);
  float var  = fmaxf(r.y * (1.f / P_) - mean * mean, 0.f);
  float rstd = rsqrtf(var + 1e-5f);
  __shared__ float shv[P_];
  shv[t] = (d - mean) * rstd * lns[t] + lnb[t];
  __syncthreads();
  if (t < NRAT){
    float s = 0.f;
    for (int p = 0; p < P_; ++p) s += shv[p] * Wse[p * NRAT + t];
    out[(size_t)ba * NRAT + t] = s;
  }
}

// ---------------------------------------------- K6: echo x -> out (fallback)
__global__ void copy_k(const float4* __restrict__ src, float4* __restrict__ dst){
  size_t i = (size_t)blockIdx.x * 256 + threadIdx.x;
  dst[i] = src[i];
}

// --------------------------------------------------------------------------
extern "C" void kernel_launch(void* const* d_in, const int* in_sizes, int n_in,
                              void* d_out, int out_size, void* d_ws, size_t ws_size,
                              hipStream_t stream) {
  const float* x        = (const float*)d_in[0];
  const int*   p_index  = (const int*)d_in[2];
  const float* ln_a_s   = (const float*)d_in[4];
  const float* ln_a_b   = (const float*)d_in[5];
  const float* W_a      = (const float*)d_in[6];
  const float* ln_s_s   = (const float*)d_in[7];
  const float* ln_s_b   = (const float*)d_in[8];
  const float* W_s      = (const float*)d_in[9];
  const float* ln_asp_s = (const float*)d_in[10];
  const float* ln_asp_b = (const float*)d_in[11];
  const float* W_asp    = (const float*)d_in[12];
  const float* ln_se_s  = (const float*)d_in[13];
  const float* ln_se_b  = (const float*)d_in[14];
  const float* W_se     = (const float*)d_in[15];

  float* out_result = (float*)d_out;                     // 640 f32
  float* out_echo   = out_result + 640;                  // 33.5M f32 (134 MB)
  float* out_adoc   = out_echo + (size_t)M_ * H_;        // 4608 f32

  char* ws = (char*)d_ws;
  u16*   WcT   = (u16*)ws;   ws += (size_t)N_ * H_ * 2;        // 1 MB
  float* biasc = (float*)ws; ws += (size_t)N_ * 4;             // 2 KB
  int*   pi    = (int*)ws;   ws += (size_t)B_ * S_ * 4;        // 2 KB
  float* sent  = (float*)ws; ws += (size_t)B_ * S_ * N_ * 4;   // 1 MB
  float* aw    = (float*)ws; ws += (size_t)B_ * S_ * NASP * 4; // 16 KB

  // proj (33.5 MB) + xhat (67 MB): prefer workspace (lets stats_xhat fuse the
  // echo write and drop copy_k's 134 MB re-read). Fallback: carve them out of
  // the echo output region and write echo last (round-3 verified layout).
  size_t small_used = (size_t)(ws - (char*)d_ws);
  size_t big_need   = small_used + (size_t)M_ * N_ * 2 + (size_t)M_ * H_ * 2;
  bool   big_ws     = ws_size >= big_need;

  u16* proj; u16* xhat;
  if (big_ws){
    proj = (u16*)ws;
    xhat = proj + (size_t)M_ * N_;
  } else {
    proj = (u16*)out_echo;
    xhat = proj + (size_t)M_ * N_;
  }

  fold_k<<<N_, 256, 0, stream>>>(W_a, W_s, ln_a_s, ln_a_b, ln_s_s, ln_s_b, WcT, biasc);
  markers_k<<<B_, 64, 0, stream>>>(p_index, pi);
  if (big_ws)
    stats_xhat_k<true ><<<M_, 256, 0, stream>>>(x, xhat, (float4*)out_echo);
  else
    stats_xhat_k<false><<<M_, 256, 0, stream>>>(x, xhat, nullptr);
  gemm_k<<<1024, 256, 0, stream>>>(xhat, WcT, biasc, proj);
  segmean_k<<<dim3(B_, S_), 1024, 0, stream>>>(proj, pi, sent);
  aspect_k<<<B_ * S_, 256, 0, stream>>>(sent, ln_asp_s, ln_asp_b, W_asp, out_adoc, aw);
  result_k<<<B_ * NASP, 256, 0, stream>>>(sent, aw, ln_se_s, ln_se_b, W_se, out_result);
  if (!big_ws)
    copy_k<<<(M_ * H_ / 4) / 256, 256, 0, stream>>>((const float4*)x, (float4*)out_echo);
}

// Round 5
// 400.482 us; speedup vs baseline: 1.0309x; 1.0309x over previous
//
#include <hip/hip_runtime.h>
#include <cstdint>
#include <cstddef>

#define B_   16
#define L_   2048
#define H_   1024
#define S_   32
#define P_   256
#define NASP 8
#define NRAT 5
#define M_   (B_*L_)   /* 32768 */
#define N_   (2*P_)    /* 512  */

typedef unsigned short u16;
typedef __bf16 bf16;
typedef u16  u16x4  __attribute__((ext_vector_type(4)));
typedef u16  u16x8  __attribute__((ext_vector_type(8)));
typedef bf16 bf16x8 __attribute__((ext_vector_type(8)));
typedef float f32x4 __attribute__((ext_vector_type(4)));

// f32 -> bf16 bits (round-to-nearest-even), bf16 bits -> f32.
__device__ __forceinline__ u16 f2b(float f){
  unsigned int u = __float_as_uint(f);
  u += 0x7FFFu + ((u >> 16) & 1u);
  return (u16)(u >> 16);
}
__device__ __forceinline__ float b2f(u16 v){
  return __uint_as_float(((unsigned int)v) << 16);
}

// async global->LDS, 16B per lane; LDS dest is wave-uniform base + lane*16.
__device__ __forceinline__ void gload_lds16(const u16* g, u16* l){
  __builtin_amdgcn_global_load_lds(
      (const __attribute__((address_space(1))) unsigned int*)g,
      (__attribute__((address_space(3))) unsigned int*)l, 16, 0, 0);
}

// ---------------------------------------------------------------- utilities
__device__ __forceinline__ float2 block_reduce2(float a, float b){
  __shared__ float sh[8];
  #pragma unroll
  for (int o = 32; o > 0; o >>= 1){
    a += __shfl_down(a, o, 64);
    b += __shfl_down(b, o, 64);
  }
  int w = threadIdx.x >> 6;
  if ((threadIdx.x & 63) == 0){ sh[w] = a; sh[w + 4] = b; }
  __syncthreads();
  float2 r;
  r.x = sh[0] + sh[1] + sh[2] + sh[3];
  r.y = sh[4] + sh[5] + sh[6] + sh[7];
  __syncthreads();
  return r;
}

// ------------------------------------------------- K0a: fold LN into weights
__global__ void fold_k(const float* __restrict__ Wa, const float* __restrict__ Ws,
                       const float* __restrict__ sa, const float* __restrict__ ba,
                       const float* __restrict__ ss, const float* __restrict__ bs,
                       u16* __restrict__ WcT, float* __restrict__ biasc){
  int n = blockIdx.x;                 // 0..511
  const float* W; const float* sc; const float* bi; int col;
  if (n < P_){ W = Wa; sc = sa; bi = ba; col = n; }
  else       { W = Ws; sc = ss; bi = bs; col = n - P_; }
  float bacc = 0.f;
  #pragma unroll
  for (int i = 0; i < 4; ++i){
    int k = threadIdx.x + i * 256;
    float w = W[(size_t)k * P_ + col];
    WcT[(size_t)n * H_ + k] = f2b(w * sc[k]);
    bacc += w * bi[k];
  }
  float2 r = block_reduce2(bacc, 0.f);
  if (threadIdx.x == 0) biasc[n] = r.x;
}

// --------------------------------------------- K0b: sentence marker indices
__global__ void markers_k(const int* __restrict__ p_index, int* __restrict__ pi){
  int b = blockIdx.x;
  int lane = threadIdx.x;             // 64 threads = 1 wave
  int cnt = 0;
  for (int c = 0; c < L_ / 64; ++c){
    int pos = c * 64 + lane;
    bool f = p_index[(size_t)b * L_ + pos] > 0;
    unsigned long long m = __ballot(f);
    int before = __popcll(m & ((1ull << lane) - 1ull));
    if (f){
      int idx = cnt + before;
      if (idx < S_) pi[b * S_ + idx] = pos;
    }
    cnt += __popcll(m);
  }
}

// -------------------- K1: fused per-row LN stats + normalize -> bf16 xhat
// FUSE_ECHO: also emit the verbatim copy of x into the echo output, saving
// the separate copy_k 134MB re-read (only used when proj/xhat live in ws).
template<bool FUSE_ECHO>
__global__ void stats_xhat_k(const float* __restrict__ x, u16* __restrict__ xhat,
                             float4* __restrict__ echo){
  int row = blockIdx.x;
  int t = threadIdx.x;
  float4 v = ((const float4*)(x + (size_t)row * H_))[t];
  if (FUSE_ECHO) echo[(size_t)row * (H_ / 4) + t] = v;
  float s  = v.x + v.y + v.z + v.w;
  float ss = v.x*v.x + v.y*v.y + v.z*v.z + v.w*v.w;
  float2 r = block_reduce2(s, ss);
  float mean = r.x * (1.f / H_);
  float var  = fmaxf(r.y * (1.f / H_) - mean * mean, 0.f);
  float rstd = rsqrtf(var + 1e-5f);
  u16x4 o;
  o[0] = f2b((v.x - mean) * rstd);
  o[1] = f2b((v.y - mean) * rstd);
  o[2] = f2b((v.z - mean) * rstd);
  o[3] = f2b((v.w - mean) * rstd);
  ((u16x4*)(xhat + (size_t)row * H_))[t] = o;
}

// --------------------------- K2: GEMM (bf16 A from xhat) + bias + GELU
// 128x128 tile, BK=64, 4 waves (2x2), 2x(4x4) 16x16x32 MFMA per K-step.
// Single-buffered serial schedule (r3 structure — compiler drains vmcnt at
// the barrier; explicit dbuf prefetch regressed in r4 because the compiler
// inserts vmcnt(0) before ds_read to guard LDS aliasing). BK=64 halves the
// number of drain stalls and doubles MFMA per barrier (32 vs 16).
// LDS rows are 128B -> guide's canonical 32-way conflict; fix chunk^=(row&7)
// applied BOTH sides: linear LDS dest + inverse-swizzled global SOURCE +
// swizzled ds_read (rule #21).
// XCD swizzle: 4 n-tiles of one m-tile adjacent on one XCD -> A L2-resident.
__global__ __launch_bounds__(256) void gemm_k(const u16* __restrict__ xhat,
                                              const u16* __restrict__ WcT,
                                              const float* __restrict__ biasc,
                                              u16* __restrict__ proj){
  __shared__ __align__(16) u16 As[128 * 64];   // 16 KB, [row][chunk] 128B rows
  __shared__ __align__(16) u16 Bs[128 * 64];   // 16 KB
  int t = threadIdx.x;
  unsigned int l = blockIdx.x;          // 0..1023
  unsigned int xcd  = l & 7;
  unsigned int slot = l >> 3;           // 0..127
  int nbase = (int)(slot & 3) * 128;
  int mbase = (int)(xcd * 32 + (slot >> 2)) * 128;

  int w = t >> 6, lane = t & 63;
  int wr = w >> 1, wc = w & 1;
  int quad = lane >> 4, l15 = lane & 15;

  // Staging: instr j (0..15) covers rows j*8..j*8+7 (8 rows x 128B = 1KB).
  // Wave w issues j = w*4..w*4+3 for A and for B. Lane -> row j*8+(lane>>3),
  // dest chunk lane&7 (linear); source chunk g = (lane&7) ^ (row&7)
  // = (lane&7) ^ (lane>>3).
  int rin = lane >> 3;                  // row within instr, 0..7
  int g = (lane & 7) ^ rin;             // inverse-swizzled source chunk
  const u16* gA[4]; const u16* gB[4]; u16* lA[4]; u16* lB[4];
  #pragma unroll
  for (int i = 0; i < 4; ++i){
    int r = w * 32 + i * 8 + rin;       // row in tile, 0..127
    gA[i] = xhat + (size_t)(mbase + r) * H_ + g * 8;
    gB[i] = WcT  + (size_t)(nbase + r) * H_ + g * 8;
    lA[i] = As + (w * 4 + i) * 512;     // 1KB = 512 u16 per instr
    lB[i] = Bs + (w * 4 + i) * 512;
  }

  f32x4 acc[4][4] = {};

  for (int kk = 0; kk < H_; kk += 64){
    __syncthreads();
    #pragma unroll
    for (int i = 0; i < 4; ++i){
      gload_lds16(gA[i] + kk, lA[i]);
      gload_lds16(gB[i] + kk, lB[i]);
    }
    __syncthreads();   // compiler drains vmcnt before barrier

    #pragma unroll
    for (int s = 0; s < 2; ++s){        // two K=32 subtiles of the BK=64 step
      bf16x8 af[4], bfr[4];
      #pragma unroll
      for (int im = 0; im < 4; ++im){
        int R = wr * 64 + im * 16 + l15;
        int c = (s * 4 + quad) ^ (R & 7);
        af[im] = *reinterpret_cast<const bf16x8*>(&As[R * 64 + c * 8]);
      }
      #pragma unroll
      for (int in = 0; in < 4; ++in){
        int R = wc * 64 + in * 16 + l15;
        int c = (s * 4 + quad) ^ (R & 7);
        bfr[in] = *reinterpret_cast<const bf16x8*>(&Bs[R * 64 + c * 8]);
      }
      #pragma unroll
      for (int im = 0; im < 4; ++im)
        #pragma unroll
        for (int in = 0; in < 4; ++in)
          acc[im][in] = __builtin_amdgcn_mfma_f32_16x16x32_bf16(af[im], bfr[in], acc[im][in], 0, 0, 0);
    }
  }

  // epilogue: bias + exact gelu + bf16 store
  #pragma unroll
  for (int in = 0; in < 4; ++in){
    int col = nbase + wc * 64 + in * 16 + l15;
    float bv = biasc[col];
    #pragma unroll
    for (int im = 0; im < 4; ++im){
      #pragma unroll
      for (int r = 0; r < 4; ++r){
        int rowg = mbase + wr * 64 + im * 16 + quad * 4 + r;
        float vv = acc[im][in][r] + bv;
        float gl = 0.5f * vv * (1.0f + erff(vv * 0.70710678118654752f));
        proj[(size_t)rowg * N_ + col] = f2b(gl);
      }
    }
  }
}

// ------------------------------------------------- K3: segment (span) means
// 1024 threads = 16 waves per block; each wave reads one FULL 1KB row
// (64 lanes x 16B), 16 rows in flight per iteration. 512 blocks x 1024 thr
// = exactly 2 blocks/CU = 32 waves/CU. Cross-wave reduce through 32KB LDS.
__global__ __launch_bounds__(1024) void segmean_k(const u16* __restrict__ proj,
                                                  const int* __restrict__ pi,
                                                  float* __restrict__ sent){
  int b = blockIdx.x, j = blockIdx.y;
  int t = threadIdx.x;
  int rg   = t >> 6;        // 0..15 (wave id = row group)
  int lane = t & 63;        // lane covers cols [lane*8, lane*8+8)
  int end   = pi[b * S_ + j];
  int start = (j == 0) ? 0 : (pi[b * S_ + j - 1] + 1);
  end   = min(max(end, 0), L_);
  start = min(max(start, 0), end);
  int cnt = max(end - start, 1);
  float inv = 1.0f / (float)cnt;

  float s[8] = {};
  const u16* base = proj + ((size_t)b * L_ + start) * N_ + lane * 8;
  for (int r = rg; r < cnt; r += 16){
    u16x8 v = *reinterpret_cast<const u16x8*>(base + (size_t)r * N_);
    #pragma unroll
    for (int k = 0; k < 8; ++k) s[k] += b2f(v[k]);
  }

  __shared__ float sh[16][N_];           // 32 KB
  #pragma unroll
  for (int k = 0; k < 8; ++k) sh[rg][lane * 8 + k] = s[k];
  __syncthreads();

  if (t < N_){
    float acc = 0.f;
    #pragma unroll
    for (int g = 0; g < 16; ++g) acc += sh[g][t];
    sent[((size_t)b * S_ + j) * N_ + t] = acc * inv;
  }
}

// --------------------- K4: aspect head: LN + (256x9) matmul + softmax
__global__ void aspect_k(const float* __restrict__ sent,
                         const float* __restrict__ lns, const float* __restrict__ lnb,
                         const float* __restrict__ Wasp,
                         float* __restrict__ out_adoc, float* __restrict__ aw){
  int sidx = blockIdx.x;   // 0..511
  int t = threadIdx.x;
  float a = sent[(size_t)sidx * N_ + t];        // a-branch = cols [0,256)
  float2 r = block_reduce2(a, a * a);
  float mean = r.x * (1.f / P_);
  float var  = fmaxf(r.y * (1.f / P_) - mean * mean, 0.f);
  float rstd = rsqrtf(var + 1e-5f);
  __shared__ float shv[P_];
  shv[t] = (a - mean) * rstd * lns[t] + lnb[t];
  __syncthreads();
  __shared__ float lg[NASP + 1];
  if (t < NASP + 1){
    float acc = 0.f;
    for (int p = 0; p < P_; ++p) acc += shv[p] * Wasp[p * (NASP + 1) + t];
    lg[t] = acc;
  }
  __syncthreads();
  __shared__ float pr[NASP + 1];
  if (t == 0){
    float m = lg[0];
    #pragma unroll
    for (int i = 1; i < NASP + 1; ++i) m = fmaxf(m, lg[i]);
    float s = 0.f;
    #pragma unroll
    for (int i = 0; i < NASP + 1; ++i){ float e = expf(lg[i] - m); pr[i] = e; s += e; }
    float is = 1.f / s;
    #pragma unroll
    for (int i = 0; i < NASP + 1; ++i) pr[i] *= is;
  }
  __syncthreads();
  if (t < NASP + 1) out_adoc[(size_t)sidx * (NASP + 1) + t] = pr[t];
  if (t < NASP)     aw[(size_t)sidx * NASP + t] = pr[t];
}

// ---------- K5: doc pooling + LN + (256x5) matmul -> result
__global__ void result_k(const float* __restrict__ sent, const float* __restrict__ aw,
                         const float* __restrict__ lns, const float* __restrict__ lnb,
                         const float* __restrict__ Wse, float* __restrict__ out){
  int ba = blockIdx.x;          // b*8 + aspect
  int b = ba >> 3, a = ba & 7;
  int t = threadIdx.x;
  float acc = 0.f, wsum = 0.f;
  for (int s2 = 0; s2 < S_; ++s2){
    float w = aw[((size_t)(b * S_ + s2)) * NASP + a];
    acc  += w * sent[((size_t)(b * S_ + s2)) * N_ + P_ + t];  // s-branch
    wsum += w;
  }
  float d = acc / fmaxf(wsum, 1e-20f);
  float2 r = block_reduce2(d, d * d);
  float mean = r.x * (1.f / P_);
  float var  = fmaxf(r.y * (1.f / P_) - mean * mean, 0.f);
  float rstd = rsqrtf(var + 1e-5f);
  __shared__ float shv[P_];
  shv[t] = (d - mean) * rstd * lns[t] + lnb[t];
  __syncthreads();
  if (t < NRAT){
    float s = 0.f;
    for (int p = 0; p < P_; ++p) s += shv[p] * Wse[p * NRAT + t];
    out[(size_t)ba * NRAT + t] = s;
  }
}

// ---------------------------------------------- K6: echo x -> out (fallback)
__global__ void copy_k(const float4* __restrict__ src, float4* __restrict__ dst){
  size_t i = (size_t)blockIdx.x * 256 + threadIdx.x;
  dst[i] = src[i];
}

// --------------------------------------------------------------------------
extern "C" void kernel_launch(void* const* d_in, const int* in_sizes, int n_in,
                              void* d_out, int out_size, void* d_ws, size_t ws_size,
                              hipStream_t stream) {
  const float* x        = (const float*)d_in[0];
  const int*   p_index  = (const int*)d_in[2];
  const float* ln_a_s   = (const float*)d_in[4];
  const float* ln_a_b   = (const float*)d_in[5];
  const float* W_a      = (const float*)d_in[6];
  const float* ln_s_s   = (const float*)d_in[7];
  const float* ln_s_b   = (const float*)d_in[8];
  const float* W_s      = (const float*)d_in[9];
  const float* ln_asp_s = (const float*)d_in[10];
  const float* ln_asp_b = (const float*)d_in[11];
  const float* W_asp    = (const float*)d_in[12];
  const float* ln_se_s  = (const float*)d_in[13];
  const float* ln_se_b  = (const float*)d_in[14];
  const float* W_se     = (const float*)d_in[15];

  float* out_result = (float*)d_out;                     // 640 f32
  float* out_echo   = out_result + 640;                  // 33.5M f32 (134 MB)
  float* out_adoc   = out_echo + (size_t)M_ * H_;        // 4608 f32

  char* ws = (char*)d_ws;
  u16*   WcT   = (u16*)ws;   ws += (size_t)N_ * H_ * 2;        // 1 MB
  float* biasc = (float*)ws; ws += (size_t)N_ * 4;             // 2 KB
  int*   pi    = (int*)ws;   ws += (size_t)B_ * S_ * 4;        // 2 KB
  float* sent  = (float*)ws; ws += (size_t)B_ * S_ * N_ * 4;   // 1 MB
  float* aw    = (float*)ws; ws += (size_t)B_ * S_ * NASP * 4; // 16 KB

  // proj (33.5 MB) + xhat (67 MB): prefer workspace (lets stats_xhat fuse the
  // echo write and drop copy_k's 134 MB re-read). Fallback: carve them out of
  // the echo output region and write echo last (round-3 verified layout).
  size_t small_used = (size_t)(ws - (char*)d_ws);
  size_t big_need   = small_used + (size_t)M_ * N_ * 2 + (size_t)M_ * H_ * 2;
  bool   big_ws     = ws_size >= big_need;

  u16* proj; u16* xhat;
  if (big_ws){
    proj = (u16*)ws;
    xhat = proj + (size_t)M_ * N_;
  } else {
    proj = (u16*)out_echo;
    xhat = proj + (size_t)M_ * N_;
  }

  fold_k<<<N_, 256, 0, stream>>>(W_a, W_s, ln_a_s, ln_a_b, ln_s_s, ln_s_b, WcT, biasc);
  markers_k<<<B_, 64, 0, stream>>>(p_index, pi);
  if (big_ws)
    stats_xhat_k<true ><<<M_, 256, 0, stream>>>(x, xhat, (float4*)out_echo);
  else
    stats_xhat_k<false><<<M_, 256, 0, stream>>>(x, xhat, nullptr);
  gemm_k<<<1024, 256, 0, stream>>>(xhat, WcT, biasc, proj);
  segmean_k<<<dim3(B_, S_), 1024, 0, stream>>>(proj, pi, sent);
  aspect_k<<<B_ * S_, 256, 0, stream>>>(sent, ln_asp_s, ln_asp_b, W_asp, out_adoc, aw);
  result_k<<<B_ * NASP, 256, 0, stream>>>(sent, aw, ln_se_s, ln_se_b, W_se, out_result);
  if (!big_ws)
    copy_k<<<(M_ * H_ / 4) / 256, 256, 0, stream>>>((const float4*)x, (float4*)out_echo);
}

// Round 6
// 399.565 us; speedup vs baseline: 1.0333x; 1.0023x over previous
//
#include <hip/hip_runtime.h>
#include <cstdint>
#include <cstddef>

#define B_   16
#define L_   2048
#define H_   1024
#define S_   32
#define P_   256
#define NASP 8
#define NRAT 5
#define M_   (B_*L_)   /* 32768 */
#define N_   (2*P_)    /* 512  */

typedef unsigned short u16;
typedef __bf16 bf16;
typedef u16  u16x4  __attribute__((ext_vector_type(4)));
typedef u16  u16x8  __attribute__((ext_vector_type(8)));
typedef bf16 bf16x8 __attribute__((ext_vector_type(8)));
typedef float f32x4 __attribute__((ext_vector_type(4)));

// f32 -> bf16 bits (round-to-nearest-even), bf16 bits -> f32.
__device__ __forceinline__ u16 f2b(float f){
  unsigned int u = __float_as_uint(f);
  u += 0x7FFFu + ((u >> 16) & 1u);
  return (u16)(u >> 16);
}
__device__ __forceinline__ float b2f(u16 v){
  return __uint_as_float(((unsigned int)v) << 16);
}

// async global->LDS, 16B per lane; LDS dest is wave-uniform base + lane*16.
__device__ __forceinline__ void gload_lds16(const u16* g, u16* l){
  __builtin_amdgcn_global_load_lds(
      (const __attribute__((address_space(1))) unsigned int*)g,
      (__attribute__((address_space(3))) unsigned int*)l, 16, 0, 0);
}

// ---------------------------------------------------------------- utilities
__device__ __forceinline__ float2 block_reduce2(float a, float b){
  __shared__ float sh[8];
  #pragma unroll
  for (int o = 32; o > 0; o >>= 1){
    a += __shfl_down(a, o, 64);
    b += __shfl_down(b, o, 64);
  }
  int w = threadIdx.x >> 6;
  if ((threadIdx.x & 63) == 0){ sh[w] = a; sh[w + 4] = b; }
  __syncthreads();
  float2 r;
  r.x = sh[0] + sh[1] + sh[2] + sh[3];
  r.y = sh[4] + sh[5] + sh[6] + sh[7];
  __syncthreads();
  return r;
}

// ------------------------------------------------- K0a: fold LN into weights
__global__ void fold_k(const float* __restrict__ Wa, const float* __restrict__ Ws,
                       const float* __restrict__ sa, const float* __restrict__ ba,
                       const float* __restrict__ ss, const float* __restrict__ bs,
                       u16* __restrict__ WcT, float* __restrict__ biasc){
  int n = blockIdx.x;                 // 0..511
  const float* W; const float* sc; const float* bi; int col;
  if (n < P_){ W = Wa; sc = sa; bi = ba; col = n; }
  else       { W = Ws; sc = ss; bi = bs; col = n - P_; }
  float bacc = 0.f;
  #pragma unroll
  for (int i = 0; i < 4; ++i){
    int k = threadIdx.x + i * 256;
    float w = W[(size_t)k * P_ + col];
    WcT[(size_t)n * H_ + k] = f2b(w * sc[k]);
    bacc += w * bi[k];
  }
  float2 r = block_reduce2(bacc, 0.f);
  if (threadIdx.x == 0) biasc[n] = r.x;
}

// --------------------------------------------- K0b: sentence marker indices
__global__ void markers_k(const int* __restrict__ p_index, int* __restrict__ pi){
  int b = blockIdx.x;
  int lane = threadIdx.x;             // 64 threads = 1 wave
  int cnt = 0;
  for (int c = 0; c < L_ / 64; ++c){
    int pos = c * 64 + lane;
    bool f = p_index[(size_t)b * L_ + pos] > 0;
    unsigned long long m = __ballot(f);
    int before = __popcll(m & ((1ull << lane) - 1ull));
    if (f){
      int idx = cnt + before;
      if (idx < S_) pi[b * S_ + idx] = pos;
    }
    cnt += __popcll(m);
  }
}

// -------------------- K1: fused per-row LN stats + normalize -> bf16 xhat
// FUSE_ECHO: also emit the verbatim copy of x into the echo output, saving
// the separate copy_k 134MB re-read (only used when proj/xhat live in ws).
template<bool FUSE_ECHO>
__global__ void stats_xhat_k(const float* __restrict__ x, u16* __restrict__ xhat,
                             float4* __restrict__ echo){
  int row = blockIdx.x;
  int t = threadIdx.x;
  float4 v = ((const float4*)(x + (size_t)row * H_))[t];
  if (FUSE_ECHO) echo[(size_t)row * (H_ / 4) + t] = v;
  float s  = v.x + v.y + v.z + v.w;
  float ss = v.x*v.x + v.y*v.y + v.z*v.z + v.w*v.w;
  float2 r = block_reduce2(s, ss);
  float mean = r.x * (1.f / H_);
  float var  = fmaxf(r.y * (1.f / H_) - mean * mean, 0.f);
  float rstd = rsqrtf(var + 1e-5f);
  u16x4 o;
  o[0] = f2b((v.x - mean) * rstd);
  o[1] = f2b((v.y - mean) * rstd);
  o[2] = f2b((v.z - mean) * rstd);
  o[3] = f2b((v.w - mean) * rstd);
  ((u16x4*)(xhat + (size_t)row * H_))[t] = o;
}

// --------------------------- K2: GEMM (bf16 A from xhat) + bias + GELU
// 256x256 tile, BK=64, 8 waves (2M x 4N), per-wave output 128x64
// (acc[8][4] of 16x16 frags). The bigger per-wave tile is the lever: 24KB of
// ds_read per 64 MFMA vs the old 16KB per 32 -> 2.7x less LDS traffic/FLOP
// (the r5 structure was LDS-throughput-bound, not schedule-bound).
// Serial 2-barrier schedule kept (r4 showed explicit dbuf regresses: the
// compiler guards gload_lds/ds_read aliasing with vmcnt(0)).
// Chunk-XOR swizzle (chunk ^= row&7) both sides: linear LDS dest +
// inverse-swizzled global SOURCE + swizzled ds_read (rule #21; measured
// 0 bank conflicts in r5 with the same math).
// Grid 256 blocks = 1/CU exactly; XCD swizzle keeps the 2 n-tiles of one
// m-tile on one XCD (A-tile L2-resident for the 2nd block).
__global__ __launch_bounds__(512, 2) void gemm_k(const u16* __restrict__ xhat,
                                                 const u16* __restrict__ WcT,
                                                 const float* __restrict__ biasc,
                                                 u16* __restrict__ proj){
  __shared__ __align__(16) u16 As[256 * 64];   // 32 KB, [row][chunk] 128B rows
  __shared__ __align__(16) u16 Bs[256 * 64];   // 32 KB
  int t = threadIdx.x;
  unsigned int l = blockIdx.x;          // 0..255
  unsigned int xcd  = l & 7;
  unsigned int slot = l >> 3;           // 0..31
  int nbase = (int)(slot & 1) * 256;
  int mbase = (int)(xcd * 16 + (slot >> 1)) * 256;

  int w = t >> 6, lane = t & 63;        // w = 0..7
  int wr = w >> 2, wc = w & 3;          // 2M x 4N wave grid
  int quad = lane >> 4, l15 = lane & 15;

  // Staging: 32 instrs/matrix/step, 4 per wave. Instr j = w*4+i covers rows
  // j*8..j*8+7 (8 rows x 128B = 1KB). Lane -> row j*8+(lane>>3); dest chunk
  // lane&7 (linear); source chunk g = (lane&7) ^ (row&7) = (lane&7)^(lane>>3).
  int rin = lane >> 3;                  // row within instr, 0..7
  int g = (lane & 7) ^ rin;             // inverse-swizzled source chunk
  const u16* gA[4]; const u16* gB[4]; u16* lA[4]; u16* lB[4];
  #pragma unroll
  for (int i = 0; i < 4; ++i){
    int r = w * 32 + i * 8 + rin;       // row in tile, 0..255
    gA[i] = xhat + (size_t)(mbase + r) * H_ + g * 8;
    gB[i] = WcT  + (size_t)(nbase + r) * H_ + g * 8;
    lA[i] = As + (w * 4 + i) * 512;     // 1KB = 512 u16 per instr
    lB[i] = Bs + (w * 4 + i) * 512;
  }

  f32x4 acc[8][4] = {};

  for (int kk = 0; kk < H_; kk += 64){
    __syncthreads();
    #pragma unroll
    for (int i = 0; i < 4; ++i){
      gload_lds16(gA[i] + kk, lA[i]);
      gload_lds16(gB[i] + kk, lB[i]);
    }
    __syncthreads();   // compiler drains vmcnt before barrier

    #pragma unroll
    for (int s = 0; s < 2; ++s){        // two K=32 subtiles of the BK=64 step
      bf16x8 af[8], bfr[4];
      #pragma unroll
      for (int im = 0; im < 8; ++im){
        int R = wr * 128 + im * 16 + l15;
        int c = (s * 4 + quad) ^ (R & 7);
        af[im] = *reinterpret_cast<const bf16x8*>(&As[R * 64 + c * 8]);
      }
      #pragma unroll
      for (int in = 0; in < 4; ++in){
        int R = wc * 64 + in * 16 + l15;
        int c = (s * 4 + quad) ^ (R & 7);
        bfr[in] = *reinterpret_cast<const bf16x8*>(&Bs[R * 64 + c * 8]);
      }
      #pragma unroll
      for (int im = 0; im < 8; ++im)
        #pragma unroll
        for (int in = 0; in < 4; ++in)
          acc[im][in] = __builtin_amdgcn_mfma_f32_16x16x32_bf16(af[im], bfr[in], acc[im][in], 0, 0, 0);
    }
  }

  // epilogue: bias + exact gelu + bf16 store
  #pragma unroll
  for (int in = 0; in < 4; ++in){
    int col = nbase + wc * 64 + in * 16 + l15;
    float bv = biasc[col];
    #pragma unroll
    for (int im = 0; im < 8; ++im){
      #pragma unroll
      for (int r = 0; r < 4; ++r){
        int rowg = mbase + wr * 128 + im * 16 + quad * 4 + r;
        float vv = acc[im][in][r] + bv;
        float gl = 0.5f * vv * (1.0f + erff(vv * 0.70710678118654752f));
        proj[(size_t)rowg * N_ + col] = f2b(gl);
      }
    }
  }
}

// ------------------------------------------------- K3: segment (span) means
// 1024 threads = 16 waves per block; each wave reads one FULL 1KB row
// (64 lanes x 16B), 16 rows in flight per iteration. 512 blocks x 1024 thr
// = exactly 2 blocks/CU = 32 waves/CU. Cross-wave reduce through 32KB LDS.
__global__ __launch_bounds__(1024) void segmean_k(const u16* __restrict__ proj,
                                                  const int* __restrict__ pi,
                                                  float* __restrict__ sent){
  int b = blockIdx.x, j = blockIdx.y;
  int t = threadIdx.x;
  int rg   = t >> 6;        // 0..15 (wave id = row group)
  int lane = t & 63;        // lane covers cols [lane*8, lane*8+8)
  int end   = pi[b * S_ + j];
  int start = (j == 0) ? 0 : (pi[b * S_ + j - 1] + 1);
  end   = min(max(end, 0), L_);
  start = min(max(start, 0), end);
  int cnt = max(end - start, 1);
  float inv = 1.0f / (float)cnt;

  float s[8] = {};
  const u16* base = proj + ((size_t)b * L_ + start) * N_ + lane * 8;
  for (int r = rg; r < cnt; r += 16){
    u16x8 v = *reinterpret_cast<const u16x8*>(base + (size_t)r * N_);
    #pragma unroll
    for (int k = 0; k < 8; ++k) s[k] += b2f(v[k]);
  }

  __shared__ float sh[16][N_];           // 32 KB
  #pragma unroll
  for (int k = 0; k < 8; ++k) sh[rg][lane * 8 + k] = s[k];
  __syncthreads();

  if (t < N_){
    float acc = 0.f;
    #pragma unroll
    for (int g = 0; g < 16; ++g) acc += sh[g][t];
    sent[((size_t)b * S_ + j) * N_ + t] = acc * inv;
  }
}

// --------------------- K4: aspect head: LN + (256x9) matmul + softmax
__global__ void aspect_k(const float* __restrict__ sent,
                         const float* __restrict__ lns, const float* __restrict__ lnb,
                         const float* __restrict__ Wasp,
                         float* __restrict__ out_adoc, float* __restrict__ aw){
  int sidx = blockIdx.x;   // 0..511
  int t = threadIdx.x;
  float a = sent[(size_t)sidx * N_ + t];        // a-branch = cols [0,256)
  float2 r = block_reduce2(a, a * a);
  float mean = r.x * (1.f / P_);
  float var  = fmaxf(r.y * (1.f / P_) - mean * mean, 0.f);
  float rstd = rsqrtf(var + 1e-5f);
  __shared__ float shv[P_];
  shv[t] = (a - mean) * rstd * lns[t] + lnb[t];
  __syncthreads();
  __shared__ float lg[NASP + 1];
  if (t < NASP + 1){
    float acc = 0.f;
    for (int p = 0; p < P_; ++p) acc += shv[p] * Wasp[p * (NASP + 1) + t];
    lg[t] = acc;
  }
  __syncthreads();
  __shared__ float pr[NASP + 1];
  if (t == 0){
    float m = lg[0];
    #pragma unroll
    for (int i = 1; i < NASP + 1; ++i) m = fmaxf(m, lg[i]);
    float s = 0.f;
    #pragma unroll
    for (int i = 0; i < NASP + 1; ++i){ float e = expf(lg[i] - m); pr[i] = e; s += e; }
    float is = 1.f / s;
    #pragma unroll
    for (int i = 0; i < NASP + 1; ++i) pr[i] *= is;
  }
  __syncthreads();
  if (t < NASP + 1) out_adoc[(size_t)sidx * (NASP + 1) + t] = pr[t];
  if (t < NASP)     aw[(size_t)sidx * NASP + t] = pr[t];
}

// ---------- K5: doc pooling + LN + (256x5) matmul -> result
__global__ void result_k(const float* __restrict__ sent, const float* __restrict__ aw,
                         const float* __restrict__ lns, const float* __restrict__ lnb,
                         const float* __restrict__ Wse, float* __restrict__ out){
  int ba = blockIdx.x;          // b*8 + aspect
  int b = ba >> 3, a = ba & 7;
  int t = threadIdx.x;
  float acc = 0.f, wsum = 0.f;
  for (int s2 = 0; s2 < S_; ++s2){
    float w = aw[((size_t)(b * S_ + s2)) * NASP + a];
    acc  += w * sent[((size_t)(b * S_ + s2)) * N_ + P_ + t];  // s-branch
    wsum += w;
  }
  float d = acc / fmaxf(wsum, 1e-20f);
  float2 r = block_reduce2(d, d * d);
  float mean = r.x * (1.f / P_);
  float var  = fmaxf(r.y * (1.f / P_) - mean * mean, 0.f);
  float rstd = rsqrtf(var + 1e-5f);
  __shared__ float shv[P_];
  shv[t] = (d - mean) * rstd * lns[t] + lnb[t];
  __syncthreads();
  if (t < NRAT){
    float s = 0.f;
    for (int p = 0; p < P_; ++p) s += shv[p] * Wse[p * NRAT + t];
    out[(size_t)ba * NRAT + t] = s;
  }
}

// ---------------------------------------------- K6: echo x -> out (fallback)
__global__ void copy_k(const float4* __restrict__ src, float4* __restrict__ dst){
  size_t i = (size_t)blockIdx.x * 256 + threadIdx.x;
  dst[i] = src[i];
}

// --------------------------------------------------------------------------
extern "C" void kernel_launch(void* const* d_in, const int* in_sizes, int n_in,
                              void* d_out, int out_size, void* d_ws, size_t ws_size,
                              hipStream_t stream) {
  const float* x        = (const float*)d_in[0];
  const int*   p_index  = (const int*)d_in[2];
  const float* ln_a_s   = (const float*)d_in[4];
  const float* ln_a_b   = (const float*)d_in[5];
  const float* W_a      = (const float*)d_in[6];
  const float* ln_s_s   = (const float*)d_in[7];
  const float* ln_s_b   = (const float*)d_in[8];
  const float* W_s      = (const float*)d_in[9];
  const float* ln_asp_s = (const float*)d_in[10];
  const float* ln_asp_b = (const float*)d_in[11];
  const float* W_asp    = (const float*)d_in[12];
  const float* ln_se_s  = (const float*)d_in[13];
  const float* ln_se_b  = (const float*)d_in[14];
  const float* W_se     = (const float*)d_in[15];

  float* out_result = (float*)d_out;                     // 640 f32
  float* out_echo   = out_result + 640;                  // 33.5M f32 (134 MB)
  float* out_adoc   = out_echo + (size_t)M_ * H_;        // 4608 f32

  char* ws = (char*)d_ws;
  u16*   WcT   = (u16*)ws;   ws += (size_t)N_ * H_ * 2;        // 1 MB
  float* biasc = (float*)ws; ws += (size_t)N_ * 4;             // 2 KB
  int*   pi    = (int*)ws;   ws += (size_t)B_ * S_ * 4;        // 2 KB
  float* sent  = (float*)ws; ws += (size_t)B_ * S_ * N_ * 4;   // 1 MB
  float* aw    = (float*)ws; ws += (size_t)B_ * S_ * NASP * 4; // 16 KB

  // proj (33.5 MB) + xhat (67 MB): prefer workspace (lets stats_xhat fuse the
  // echo write and drop copy_k's 134 MB re-read). Fallback: carve them out of
  // the echo output region and write echo last (round-3 verified layout).
  size_t small_used = (size_t)(ws - (char*)d_ws);
  size_t big_need   = small_used + (size_t)M_ * N_ * 2 + (size_t)M_ * H_ * 2;
  bool   big_ws     = ws_size >= big_need;

  u16* proj; u16* xhat;
  if (big_ws){
    proj = (u16*)ws;
    xhat = proj + (size_t)M_ * N_;
  } else {
    proj = (u16*)out_echo;
    xhat = proj + (size_t)M_ * N_;
  }

  fold_k<<<N_, 256, 0, stream>>>(W_a, W_s, ln_a_s, ln_a_b, ln_s_s, ln_s_b, WcT, biasc);
  markers_k<<<B_, 64, 0, stream>>>(p_index, pi);
  if (big_ws)
    stats_xhat_k<true ><<<M_, 256, 0, stream>>>(x, xhat, (float4*)out_echo);
  else
    stats_xhat_k<false><<<M_, 256, 0, stream>>>(x, xhat, nullptr);
  gemm_k<<<256, 512, 0, stream>>>(xhat, WcT, biasc, proj);
  segmean_k<<<dim3(B_, S_), 1024, 0, stream>>>(proj, pi, sent);
  aspect_k<<<B_ * S_, 256, 0, stream>>>(sent, ln_asp_s, ln_asp_b, W_asp, out_adoc, aw);
  result_k<<<B_ * NASP, 256, 0, stream>>>(sent, aw, ln_se_s, ln_se_b, W_se, out_result);
  if (!big_ws)
    copy_k<<<(M_ * H_ / 4) / 256, 256, 0, stream>>>((const float4*)x, (float4*)out_echo);
}

// Round 7
// 393.523 us; speedup vs baseline: 1.0491x; 1.0154x over previous
//
#include <hip/hip_runtime.h>
#include <cstdint>
#include <cstddef>

#define B_   16
#define L_   2048
#define H_   1024
#define S_   32
#define P_   256
#define NASP 8
#define NRAT 5
#define M_   (B_*L_)   /* 32768 */
#define N_   (2*P_)    /* 512  */

typedef unsigned short u16;
typedef __bf16 bf16;
typedef u16  u16x4  __attribute__((ext_vector_type(4)));
typedef u16  u16x8  __attribute__((ext_vector_type(8)));
typedef bf16 bf16x8 __attribute__((ext_vector_type(8)));
typedef float f32x4 __attribute__((ext_vector_type(4)));

// f32 -> bf16 bits (round-to-nearest-even), bf16 bits -> f32.
__device__ __forceinline__ u16 f2b(float f){
  unsigned int u = __float_as_uint(f);
  u += 0x7FFFu + ((u >> 16) & 1u);
  return (u16)(u >> 16);
}
__device__ __forceinline__ float b2f(u16 v){
  return __uint_as_float(((unsigned int)v) << 16);
}

// async global->LDS, 16B per lane; LDS dest is wave-uniform base + lane*16.
__device__ __forceinline__ void gload_lds16(const u16* g, u16* l){
  __builtin_amdgcn_global_load_lds(
      (const __attribute__((address_space(1))) unsigned int*)g,
      (__attribute__((address_space(3))) unsigned int*)l, 16, 0, 0);
}

// ---------------------------------------------------------------- utilities
__device__ __forceinline__ float2 block_reduce2(float a, float b){
  __shared__ float sh[8];
  #pragma unroll
  for (int o = 32; o > 0; o >>= 1){
    a += __shfl_down(a, o, 64);
    b += __shfl_down(b, o, 64);
  }
  int w = threadIdx.x >> 6;
  if ((threadIdx.x & 63) == 0){ sh[w] = a; sh[w + 4] = b; }
  __syncthreads();
  float2 r;
  r.x = sh[0] + sh[1] + sh[2] + sh[3];
  r.y = sh[4] + sh[5] + sh[6] + sh[7];
  __syncthreads();
  return r;
}

// ------------------------------------------------- K0a: fold LN into weights
__global__ void fold_k(const float* __restrict__ Wa, const float* __restrict__ Ws,
                       const float* __restrict__ sa, const float* __restrict__ ba,
                       const float* __restrict__ ss, const float* __restrict__ bs,
                       u16* __restrict__ WcT, float* __restrict__ biasc){
  int n = blockIdx.x;                 // 0..511
  const float* W; const float* sc; const float* bi; int col;
  if (n < P_){ W = Wa; sc = sa; bi = ba; col = n; }
  else       { W = Ws; sc = ss; bi = bs; col = n - P_; }
  float bacc = 0.f;
  #pragma unroll
  for (int i = 0; i < 4; ++i){
    int k = threadIdx.x + i * 256;
    float w = W[(size_t)k * P_ + col];
    WcT[(size_t)n * H_ + k] = f2b(w * sc[k]);
    bacc += w * bi[k];
  }
  float2 r = block_reduce2(bacc, 0.f);
  if (threadIdx.x == 0) biasc[n] = r.x;
}

// --------------------------------------------- K0b: sentence marker indices
__global__ void markers_k(const int* __restrict__ p_index, int* __restrict__ pi){
  int b = blockIdx.x;
  int lane = threadIdx.x;             // 64 threads = 1 wave
  int cnt = 0;
  for (int c = 0; c < L_ / 64; ++c){
    int pos = c * 64 + lane;
    bool f = p_index[(size_t)b * L_ + pos] > 0;
    unsigned long long m = __ballot(f);
    int before = __popcll(m & ((1ull << lane) - 1ull));
    if (f){
      int idx = cnt + before;
      if (idx < S_) pi[b * S_ + idx] = pos;
    }
    cnt += __popcll(m);
  }
}

// -------------------- K1: fused per-row LN stats + normalize -> bf16 xhat
// FUSE_ECHO: also emit the verbatim copy of x into the echo output, saving
// the separate copy_k 134MB re-read (only used when proj/xhat live in ws).
template<bool FUSE_ECHO>
__global__ void stats_xhat_k(const float* __restrict__ x, u16* __restrict__ xhat,
                             float4* __restrict__ echo){
  int row = blockIdx.x;
  int t = threadIdx.x;
  float4 v = ((const float4*)(x + (size_t)row * H_))[t];
  if (FUSE_ECHO) echo[(size_t)row * (H_ / 4) + t] = v;
  float s  = v.x + v.y + v.z + v.w;
  float ss = v.x*v.x + v.y*v.y + v.z*v.z + v.w*v.w;
  float2 r = block_reduce2(s, ss);
  float mean = r.x * (1.f / H_);
  float var  = fmaxf(r.y * (1.f / H_) - mean * mean, 0.f);
  float rstd = rsqrtf(var + 1e-5f);
  u16x4 o;
  o[0] = f2b((v.x - mean) * rstd);
  o[1] = f2b((v.y - mean) * rstd);
  o[2] = f2b((v.z - mean) * rstd);
  o[3] = f2b((v.w - mean) * rstd);
  ((u16x4*)(xhat + (size_t)row * H_))[t] = o;
}

// --------------------------- K2: GEMM (bf16 A from xhat) + bias + GELU
// 256x256 tile, BK=64, 8 waves (2M x 4N), per-wave 128x64 out (acc[8][4]).
// T4 counted-vmcnt double-buffered schedule: raw s_barrier (no compiler
// vmcnt(0) drain), STAGE(tile t+2) issued right after buf frees, then
// s_waitcnt vmcnt(8) -> waits only for tile t+1's loads (issued one full
// compute phase ago), never draining the fresh prefetch. sched_barrier(0)
// after each asm wait (rule #18); setprio(1) around the MFMA cluster (T5).
// Chunk-XOR swizzle (chunk ^= row&7) both sides: linear LDS dest +
// inverse-swizzled global SOURCE + swizzled ds_read (rule #21; 0 conflicts
// measured r5/r6). Grid 256 = 1 block/CU; XCD swizzle keeps the 2 n-tiles
// of an m-tile on one XCD (A-panel L2-resident).
#define NT_ 16   /* K tiles: 1024/64 */
__global__ __launch_bounds__(512, 2) void gemm_k(const u16* __restrict__ xhat,
                                                 const u16* __restrict__ WcT,
                                                 const float* __restrict__ biasc,
                                                 u16* __restrict__ proj){
  __shared__ __align__(16) u16 As[2][256 * 64];   // 2 x 32 KB
  __shared__ __align__(16) u16 Bs[2][256 * 64];   // 2 x 32 KB
  int t = threadIdx.x;
  unsigned int l = blockIdx.x;          // 0..255
  unsigned int xcd  = l & 7;
  unsigned int slot = l >> 3;           // 0..31
  int nbase = (int)(slot & 1) * 256;
  int mbase = (int)(xcd * 16 + (slot >> 1)) * 256;

  int w = t >> 6, lane = t & 63;        // w = 0..7
  int wr = w >> 2, wc = w & 3;          // 2M x 4N wave grid
  int quad = lane >> 4, l15 = lane & 15;

  // Staging: 32 instrs/matrix/tile, 4 per wave. Instr j = w*4+i covers rows
  // j*8..j*8+7 (8 rows x 128B = 1KB). Lane -> row j*8+(lane>>3); dest chunk
  // lane&7 (linear); source chunk g = (lane&7) ^ (row&7) = (lane&7)^(lane>>3).
  int rin = lane >> 3;                  // row within instr, 0..7
  int g = (lane & 7) ^ rin;             // inverse-swizzled source chunk
  const u16* gA[4]; const u16* gB[4]; int off[4];
  #pragma unroll
  for (int i = 0; i < 4; ++i){
    int r = w * 32 + i * 8 + rin;       // row in tile, 0..255
    gA[i] = xhat + (size_t)(mbase + r) * H_ + g * 8;
    gB[i] = WcT  + (size_t)(nbase + r) * H_ + g * 8;
    off[i] = (w * 4 + i) * 512;         // 1KB = 512 u16 per instr
  }

  f32x4 acc[8][4] = {};

#define STAGE_(buf, tile) do{ int kk_ = (tile) * 64;            \
    gload_lds16(gA[0] + kk_, &As[buf][off[0]]);                 \
    gload_lds16(gA[1] + kk_, &As[buf][off[1]]);                 \
    gload_lds16(gA[2] + kk_, &As[buf][off[2]]);                 \
    gload_lds16(gA[3] + kk_, &As[buf][off[3]]);                 \
    gload_lds16(gB[0] + kk_, &Bs[buf][off[0]]);                 \
    gload_lds16(gB[1] + kk_, &Bs[buf][off[1]]);                 \
    gload_lds16(gB[2] + kk_, &Bs[buf][off[2]]);                 \
    gload_lds16(gB[3] + kk_, &Bs[buf][off[3]]);                 \
  }while(0)

  // prologue: tiles 0 and 1 in flight (16 loads/thread)
  STAGE_(0, 0);
  STAGE_(1, 1);
  asm volatile("s_waitcnt vmcnt(8)" ::: "memory");   // tile0 landed
  __builtin_amdgcn_sched_barrier(0);
  __builtin_amdgcn_s_barrier();

  for (int kt = 0; kt < NT_; ++kt){
    int cur = kt & 1;
    __builtin_amdgcn_s_setprio(1);
    #pragma unroll
    for (int s = 0; s < 2; ++s){        // two K=32 subtiles of the BK=64 tile
      bf16x8 af[8], bfr[4];
      #pragma unroll
      for (int im = 0; im < 8; ++im){
        int R = wr * 128 + im * 16 + l15;
        int c = (s * 4 + quad) ^ (R & 7);
        af[im] = *reinterpret_cast<const bf16x8*>(&As[cur][R * 64 + c * 8]);
      }
      #pragma unroll
      for (int in = 0; in < 4; ++in){
        int R = wc * 64 + in * 16 + l15;
        int c = (s * 4 + quad) ^ (R & 7);
        bfr[in] = *reinterpret_cast<const bf16x8*>(&Bs[cur][R * 64 + c * 8]);
      }
      #pragma unroll
      for (int im = 0; im < 8; ++im)
        #pragma unroll
        for (int in = 0; in < 4; ++in)
          acc[im][in] = __builtin_amdgcn_mfma_f32_16x16x32_bf16(af[im], bfr[in], acc[im][in], 0, 0, 0);
    }
    __builtin_amdgcn_s_setprio(0);
    if (kt == NT_ - 1) break;
    __builtin_amdgcn_s_barrier();        // all waves done reading buf[cur]
    if (kt + 2 < NT_){
      STAGE_(cur, kt + 2);               // refill freed buffer
      asm volatile("s_waitcnt vmcnt(8)" ::: "memory");  // tile kt+1 landed
    } else {
      asm volatile("s_waitcnt vmcnt(0)" ::: "memory");  // last tile landed
    }
    __builtin_amdgcn_sched_barrier(0);
    __builtin_amdgcn_s_barrier();        // all waves see buf[cur^1] ready
  }
#undef STAGE_

  // epilogue: bias + exact gelu + bf16 store
  #pragma unroll
  for (int in = 0; in < 4; ++in){
    int col = nbase + wc * 64 + in * 16 + l15;
    float bv = biasc[col];
    #pragma unroll
    for (int im = 0; im < 8; ++im){
      #pragma unroll
      for (int r = 0; r < 4; ++r){
        int rowg = mbase + wr * 128 + im * 16 + quad * 4 + r;
        float vv = acc[im][in][r] + bv;
        float gl = 0.5f * vv * (1.0f + erff(vv * 0.70710678118654752f));
        proj[(size_t)rowg * N_ + col] = f2b(gl);
      }
    }
  }
}

// ------------------------------------------------- K3: segment (span) means
// 1024 threads = 16 waves per block; each wave reads one FULL 1KB row
// (64 lanes x 16B), 16 rows in flight per iteration. 512 blocks x 1024 thr
// = exactly 2 blocks/CU = 32 waves/CU. Cross-wave reduce through 32KB LDS.
__global__ __launch_bounds__(1024) void segmean_k(const u16* __restrict__ proj,
                                                  const int* __restrict__ pi,
                                                  float* __restrict__ sent){
  int b = blockIdx.x, j = blockIdx.y;
  int t = threadIdx.x;
  int rg   = t >> 6;        // 0..15 (wave id = row group)
  int lane = t & 63;        // lane covers cols [lane*8, lane*8+8)
  int end   = pi[b * S_ + j];
  int start = (j == 0) ? 0 : (pi[b * S_ + j - 1] + 1);
  end   = min(max(end, 0), L_);
  start = min(max(start, 0), end);
  int cnt = max(end - start, 1);
  float inv = 1.0f / (float)cnt;

  float s[8] = {};
  const u16* base = proj + ((size_t)b * L_ + start) * N_ + lane * 8;
  for (int r = rg; r < cnt; r += 16){
    u16x8 v = *reinterpret_cast<const u16x8*>(base + (size_t)r * N_);
    #pragma unroll
    for (int k = 0; k < 8; ++k) s[k] += b2f(v[k]);
  }

  __shared__ float sh[16][N_];           // 32 KB
  #pragma unroll
  for (int k = 0; k < 8; ++k) sh[rg][lane * 8 + k] = s[k];
  __syncthreads();

  if (t < N_){
    float acc = 0.f;
    #pragma unroll
    for (int g = 0; g < 16; ++g) acc += sh[g][t];
    sent[((size_t)b * S_ + j) * N_ + t] = acc * inv;
  }
}

// --------------------- K4: aspect head: LN + (256x9) matmul + softmax
__global__ void aspect_k(const float* __restrict__ sent,
                         const float* __restrict__ lns, const float* __restrict__ lnb,
                         const float* __restrict__ Wasp,
                         float* __restrict__ out_adoc, float* __restrict__ aw){
  int sidx = blockIdx.x;   // 0..511
  int t = threadIdx.x;
  float a = sent[(size_t)sidx * N_ + t];        // a-branch = cols [0,256)
  float2 r = block_reduce2(a, a * a);
  float mean = r.x * (1.f / P_);
  float var  = fmaxf(r.y * (1.f / P_) - mean * mean, 0.f);
  float rstd = rsqrtf(var + 1e-5f);
  __shared__ float shv[P_];
  shv[t] = (a - mean) * rstd * lns[t] + lnb[t];
  __syncthreads();
  __shared__ float lg[NASP + 1];
  if (t < NASP + 1){
    float acc = 0.f;
    for (int p = 0; p < P_; ++p) acc += shv[p] * Wasp[p * (NASP + 1) + t];
    lg[t] = acc;
  }
  __syncthreads();
  __shared__ float pr[NASP + 1];
  if (t == 0){
    float m = lg[0];
    #pragma unroll
    for (int i = 1; i < NASP + 1; ++i) m = fmaxf(m, lg[i]);
    float s = 0.f;
    #pragma unroll
    for (int i = 0; i < NASP + 1; ++i){ float e = expf(lg[i] - m); pr[i] = e; s += e; }
    float is = 1.f / s;
    #pragma unroll
    for (int i = 0; i < NASP + 1; ++i) pr[i] *= is;
  }
  __syncthreads();
  if (t < NASP + 1) out_adoc[(size_t)sidx * (NASP + 1) + t] = pr[t];
  if (t < NASP)     aw[(size_t)sidx * NASP + t] = pr[t];
}

// ---------- K5: doc pooling + LN + (256x5) matmul -> result
__global__ void result_k(const float* __restrict__ sent, const float* __restrict__ aw,
                         const float* __restrict__ lns, const float* __restrict__ lnb,
                         const float* __restrict__ Wse, float* __restrict__ out){
  int ba = blockIdx.x;          // b*8 + aspect
  int b = ba >> 3, a = ba & 7;
  int t = threadIdx.x;
  float acc = 0.f, wsum = 0.f;
  for (int s2 = 0; s2 < S_; ++s2){
    float w = aw[((size_t)(b * S_ + s2)) * NASP + a];
    acc  += w * sent[((size_t)(b * S_ + s2)) * N_ + P_ + t];  // s-branch
    wsum += w;
  }
  float d = acc / fmaxf(wsum, 1e-20f);
  float2 r = block_reduce2(d, d * d);
  float mean = r.x * (1.f / P_);
  float var  = fmaxf(r.y * (1.f / P_) - mean * mean, 0.f);
  float rstd = rsqrtf(var + 1e-5f);
  __shared__ float shv[P_];
  shv[t] = (d - mean) * rstd * lns[t] + lnb[t];
  __syncthreads();
  if (t < NRAT){
    float s = 0.f;
    for (int p = 0; p < P_; ++p) s += shv[p] * Wse[p * NRAT + t];
    out[(size_t)ba * NRAT + t] = s;
  }
}

// ---------------------------------------------- K6: echo x -> out (fallback)
__global__ void copy_k(const float4* __restrict__ src, float4* __restrict__ dst){
  size_t i = (size_t)blockIdx.x * 256 + threadIdx.x;
  dst[i] = src[i];
}

// --------------------------------------------------------------------------
extern "C" void kernel_launch(void* const* d_in, const int* in_sizes, int n_in,
                              void* d_out, int out_size, void* d_ws, size_t ws_size,
                              hipStream_t stream) {
  const float* x        = (const float*)d_in[0];
  const int*   p_index  = (const int*)d_in[2];
  const float* ln_a_s   = (const float*)d_in[4];
  const float* ln_a_b   = (const float*)d_in[5];
  const float* W_a      = (const float*)d_in[6];
  const float* ln_s_s   = (const float*)d_in[7];
  const float* ln_s_b   = (const float*)d_in[8];
  const float* W_s      = (const float*)d_in[9];
  const float* ln_asp_s = (const float*)d_in[10];
  const float* ln_asp_b = (const float*)d_in[11];
  const float* W_asp    = (const float*)d_in[12];
  const float* ln_se_s  = (const float*)d_in[13];
  const float* ln_se_b  = (const float*)d_in[14];
  const float* W_se     = (const float*)d_in[15];

  float* out_result = (float*)d_out;                     // 640 f32
  float* out_echo   = out_result + 640;                  // 33.5M f32 (134 MB)
  float* out_adoc   = out_echo + (size_t)M_ * H_;        // 4608 f32

  char* ws = (char*)d_ws;
  u16*   WcT   = (u16*)ws;   ws += (size_t)N_ * H_ * 2;        // 1 MB
  float* biasc = (float*)ws; ws += (size_t)N_ * 4;             // 2 KB
  int*   pi    = (int*)ws;   ws += (size_t)B_ * S_ * 4;        // 2 KB
  float* sent  = (float*)ws; ws += (size_t)B_ * S_ * N_ * 4;   // 1 MB
  float* aw    = (float*)ws; ws += (size_t)B_ * S_ * NASP * 4; // 16 KB

  // proj (33.5 MB) + xhat (67 MB): prefer workspace (lets stats_xhat fuse the
  // echo write and drop copy_k's 134 MB re-read). Fallback: carve them out of
  // the echo output region and write echo last (round-3 verified layout).
  size_t small_used = (size_t)(ws - (char*)d_ws);
  size_t big_need   = small_used + (size_t)M_ * N_ * 2 + (size_t)M_ * H_ * 2;
  bool   big_ws     = ws_size >= big_need;

  u16* proj; u16* xhat;
  if (big_ws){
    proj = (u16*)ws;
    xhat = proj + (size_t)M_ * N_;
  } else {
    proj = (u16*)out_echo;
    xhat = proj + (size_t)M_ * N_;
  }

  fold_k<<<N_, 256, 0, stream>>>(W_a, W_s, ln_a_s, ln_a_b, ln_s_s, ln_s_b, WcT, biasc);
  markers_k<<<B_, 64, 0, stream>>>(p_index, pi);
  if (big_ws)
    stats_xhat_k<true ><<<M_, 256, 0, stream>>>(x, xhat, (float4*)out_echo);
  else
    stats_xhat_k<false><<<M_, 256, 0, stream>>>(x, xhat, nullptr);
  gemm_k<<<256, 512, 0, stream>>>(xhat, WcT, biasc, proj);
  segmean_k<<<dim3(B_, S_), 1024, 0, stream>>>(proj, pi, sent);
  aspect_k<<<B_ * S_, 256, 0, stream>>>(sent, ln_asp_s, ln_asp_b, W_asp, out_adoc, aw);
  result_k<<<B_ * NASP, 256, 0, stream>>>(sent, aw, ln_se_s, ln_se_b, W_se, out_result);
  if (!big_ws)
    copy_k<<<(M_ * H_ / 4) / 256, 256, 0, stream>>>((const float4*)x, (float4*)out_echo);
}